// Round 1
// 1496.831 us; speedup vs baseline: 1.4494x; 1.4494x over previous
//
#include <hip/hip_runtime.h>
#include <math.h>

// Problem constants
#define BB 2
#define TT 2048
#define DM 1024
#define NH 16
#define DKK 64
#define MTOT (BB*TT)        // 4096
#define BHN (BB*NH)         // 32

typedef short bf16x8 __attribute__((ext_vector_type(8)));
typedef float f32x4 __attribute__((ext_vector_type(4)));

static __device__ __forceinline__ unsigned short f32_bf16(float f) {
    union { float f; unsigned u; } v; v.f = f;
    unsigned u = v.u + 0x7fffu + ((v.u >> 16) & 1u);   // RNE
    return (unsigned short)(u >> 16);
}
static __device__ __forceinline__ float bf16_f32(unsigned short h) {
    union { unsigned u; float f; } v; v.u = (unsigned)h << 16;
    return v.f;
}
static __device__ __forceinline__ void split4(float4 v, ushort4* h, ushort4* l) {
    h->x = f32_bf16(v.x); l->x = f32_bf16(v.x - bf16_f32(h->x));
    h->y = f32_bf16(v.y); l->y = f32_bf16(v.y - bf16_f32(h->y));
    h->z = f32_bf16(v.z); l->z = f32_bf16(v.z - bf16_f32(h->z));
    h->w = f32_bf16(v.w); l->w = f32_bf16(v.w - bf16_f32(h->w));
}

// A addressing: mode 0 = x row-major [M][K]; mode 1 = gather from [B,H,T,64]
static __device__ __forceinline__ const float* aptr(const float* A, int mode, int m, int k) {
    if (mode == 0) return A + (size_t)m * 1024 + k;
    int b = m >> 11, t = m & 2047;
    int h = k >> 6, d = k & 63;
    return A + (((size_t)(b * 16 + h)) * 2048 + t) * 64 + d;
}

// ---------------------------------------------------------------------------
// C = A(4096x1024) * Bt(1024x1024)^T via bf16x3 (split-precision) MFMA.
// acc += Ah*Bh + Ah*Bl + Al*Bh  (fp32 accumulate) -> ~fp32 accuracy.
// Tile 128x128, BK=32, 256 threads = 4 waves; wave owns a 64x64 quadrant
// (4x4 fragments of v_mfma_f32_16x16x32_bf16).
// LDS: [row][k] bf16, rows of 4x 16B chunks, chunk XOR-swizzled by (row>>1)&3
// so per-quarter-wave ds_read_b128 is 2-way (8-way if linear).
// ---------------------------------------------------------------------------
__global__ __launch_bounds__(256) void gemm_bt_x3(
    const float* __restrict__ A, const float* __restrict__ Bt,
    float* __restrict__ C, int mode)
{
    __shared__ __align__(16) unsigned short Ah[128*32];
    __shared__ __align__(16) unsigned short Al[128*32];
    __shared__ __align__(16) unsigned short Bh[128*32];
    __shared__ __align__(16) unsigned short Bl[128*32];

    const int tid = threadIdx.x;
    const int m_base = blockIdx.x * 128;
    const int n_base = blockIdx.y * 128;
    const int lane = tid & 63;
    const int wave = tid >> 6;
    const int wr = wave >> 1, wc = wave & 1;     // 64x64 quadrant
    const int l16 = lane & 15, lk = lane >> 4;   // frag row/col, k-chunk

    f32x4 zero = {0.f, 0.f, 0.f, 0.f};
    f32x4 acc[4][4];
#pragma unroll
    for (int i = 0; i < 4; ++i)
#pragma unroll
        for (int j = 0; j < 4; ++j) acc[i][j] = zero;

    // Staging: 1024 float4 per tile (128 rows x 8 k-quads), 4 per thread.
    float4 ga[4], gb[4];
#pragma unroll
    for (int q = 0; q < 4; ++q) {
        int fq = tid + q * 256;
        int row = fq >> 3, kq = fq & 7;
        ga[q] = *(const float4*)aptr(A, mode, m_base + row, kq * 4);
        gb[q] = *(const float4*)(Bt + (size_t)(n_base + row) * 1024 + kq * 4);
    }

    for (int ks = 0; ks < 32; ++ks) {
        __syncthreads();   // previous iteration's frag reads complete
        // convert fp32 -> (hi,lo) bf16 and stage
#pragma unroll
        for (int q = 0; q < 4; ++q) {
            int fq = tid + q * 256;
            int row = fq >> 3, kq = fq & 7;
            int sw = (kq >> 1) ^ ((row >> 1) & 3);
            int base = row * 32 + sw * 8 + (kq & 1) * 4;
            ushort4 h, l;
            split4(ga[q], &h, &l);
            *(ushort4*)&Ah[base] = h;
            *(ushort4*)&Al[base] = l;
            split4(gb[q], &h, &l);
            *(ushort4*)&Bh[base] = h;
            *(ushort4*)&Bl[base] = l;
        }
        __syncthreads();

        // prefetch next K-step (latency hides under MFMA below)
        if (ks + 1 < 32) {
            int k0 = (ks + 1) * 32;
#pragma unroll
            for (int q = 0; q < 4; ++q) {
                int fq = tid + q * 256;
                int row = fq >> 3, kq = fq & 7;
                ga[q] = *(const float4*)aptr(A, mode, m_base + row, k0 + kq * 4);
                gb[q] = *(const float4*)(Bt + (size_t)(n_base + row) * 1024 + k0 + kq * 4);
            }
        }

        // Fragments: lane holds row (l16) x 8 consecutive k at chunk lk.
        // A and B use the same k mapping, so any k-permutation cancels.
        bf16x8 fah[4], fal[4], fbh[4], fbl[4];
#pragma unroll
        for (int i = 0; i < 4; ++i) {
            int am = wr * 64 + i * 16 + l16;
            int ao = am * 32 + ((lk ^ ((am >> 1) & 3)) * 8);
            fah[i] = *(const bf16x8*)&Ah[ao];
            fal[i] = *(const bf16x8*)&Al[ao];
            int bn = wc * 64 + i * 16 + l16;
            int bo = bn * 32 + ((lk ^ ((bn >> 1) & 3)) * 8);
            fbh[i] = *(const bf16x8*)&Bh[bo];
            fbl[i] = *(const bf16x8*)&Bl[bo];
        }
#pragma unroll
        for (int i = 0; i < 4; ++i)
#pragma unroll
            for (int j = 0; j < 4; ++j) {
                acc[i][j] = __builtin_amdgcn_mfma_f32_16x16x32_bf16(fah[i], fbh[j], acc[i][j], 0, 0, 0);
                acc[i][j] = __builtin_amdgcn_mfma_f32_16x16x32_bf16(fah[i], fbl[j], acc[i][j], 0, 0, 0);
                acc[i][j] = __builtin_amdgcn_mfma_f32_16x16x32_bf16(fal[i], fbh[j], acc[i][j], 0, 0, 0);
            }
    }

    // C/D layout (verified): col = lane&15, row = (lane>>4)*4 + reg
#pragma unroll
    for (int i = 0; i < 4; ++i) {
#pragma unroll
        for (int j = 0; j < 4; ++j) {
            int gn = n_base + wc * 64 + j * 16 + l16;
#pragma unroll
            for (int r = 0; r < 4; ++r) {
                int gm = m_base + wr * 64 + i * 16 + lk * 4 + r;
                float val = acc[i][j][r];
                if (mode == 0) {
                    int b = gm >> 11, t = gm & 2047;
                    int h = gn >> 6, d = gn & 63;
                    C[(((size_t)(b * 16 + h)) * 2048 + t) * 64 + d] = val;
                } else {
                    C[(size_t)gm * 1024 + gn] = val;
                }
            }
        }
    }
}

// ---------------------------------------------------------------------------
// Pass 1 of softmax: per (b,h, 64-row q tile), stream over all 2048 k-cols
// computing row max and row sum-exp (online). Scores recomputed in pass 2.
// (unchanged this round)
// ---------------------------------------------------------------------------
__global__ __launch_bounds__(256) void rowstats(
    const float* __restrict__ Q, const float* __restrict__ Kmat,
    float* __restrict__ rowmax, float* __restrict__ rowsum)
{
    __shared__ float Qs[64][64];    // [d][r]
    __shared__ float Ks[64][128];   // [d][c]

    const int qt = blockIdx.x;      // 0..31
    const int bh = blockIdx.y;      // 0..31
    const float* Qb = Q + ((size_t)bh * 2048 + qt * 64) * 64;
    const float* Kb = Kmat + (size_t)bh * 2048 * 64;
    const int tid = threadIdx.x;

#pragma unroll
    for (int l = 0; l < 4; ++l) {
        int idx = tid + l * 256;
        int r = idx >> 4;
        int d0 = (idx & 15) * 4;
        float4 v = *(const float4*)(Qb + (size_t)r * 64 + d0);
        Qs[d0 + 0][r] = v.x; Qs[d0 + 1][r] = v.y;
        Qs[d0 + 2][r] = v.z; Qs[d0 + 3][r] = v.w;
    }

    const int ty = tid >> 4, tx = tid & 15;
    const int r0 = ty * 4;
    float mrow[4], lrow[4];
#pragma unroll
    for (int i = 0; i < 4; ++i) { mrow[i] = -INFINITY; lrow[i] = 0.0f; }

    for (int kt = 0; kt < 16; ++kt) {
        __syncthreads();
#pragma unroll
        for (int l = 0; l < 8; ++l) {
            int idx = tid + l * 256;
            int c = idx >> 4;
            int d0 = (idx & 15) * 4;
            float4 v = *(const float4*)(Kb + ((size_t)kt * 128 + c) * 64 + d0);
            Ks[d0 + 0][c] = v.x; Ks[d0 + 1][c] = v.y;
            Ks[d0 + 2][c] = v.z; Ks[d0 + 3][c] = v.w;
        }
        __syncthreads();

        float s[4][8];
#pragma unroll
        for (int i = 0; i < 4; ++i)
#pragma unroll
            for (int j = 0; j < 8; ++j) s[i][j] = 0.0f;

        for (int d = 0; d < 64; ++d) {
            float a[4], b[8];
            *(float4*)(a)     = *(const float4*)&Qs[d][r0];
            *(float4*)(b)     = *(const float4*)&Ks[d][tx * 8];
            *(float4*)(b + 4) = *(const float4*)&Ks[d][tx * 8 + 4];
#pragma unroll
            for (int i = 0; i < 4; ++i)
#pragma unroll
                for (int j = 0; j < 8; ++j)
                    s[i][j] = fmaf(a[i], b[j], s[i][j]);
        }

#pragma unroll
        for (int i = 0; i < 4; ++i) {
            float mx = s[i][0];
#pragma unroll
            for (int j = 1; j < 8; ++j) mx = fmaxf(mx, s[i][j]);
            mx *= 0.125f;
            float mnew = fmaxf(mrow[i], mx);
            float ls = 0.0f;
#pragma unroll
            for (int j = 0; j < 8; ++j) ls += __expf(s[i][j] * 0.125f - mnew);
            lrow[i] = lrow[i] * __expf(mrow[i] - mnew) + ls;
            mrow[i] = mnew;
        }
    }

#pragma unroll
    for (int off = 1; off < 16; off <<= 1) {
#pragma unroll
        for (int i = 0; i < 4; ++i) {
            float mo = __shfl_xor(mrow[i], off);
            float lo = __shfl_xor(lrow[i], off);
            float mn = fmaxf(mrow[i], mo);
            lrow[i] = lrow[i] * __expf(mrow[i] - mn) + lo * __expf(mo - mn);
            mrow[i] = mn;
        }
    }
    if (tx == 0) {
#pragma unroll
        for (int i = 0; i < 4; ++i) {
            int r = qt * 64 + r0 + i;
            rowmax[(size_t)bh * 2048 + r] = mrow[i];
            rowsum[(size_t)bh * 2048 + r] = lrow[i];
        }
    }
}

// ---------------------------------------------------------------------------
// Pass 2: recompute scores per 64x64 tile, normalize with (rowmax, rowsum),
// write attn_weights, accumulate O = P.V.
// Change this round: K-tile and P^T share one LDS buffer (K fully consumed
// by the score phase before P^T overwrites it) -> 48 KiB/block -> 3 blocks/CU
// instead of 2. Costs one extra barrier per kt tile.
// ---------------------------------------------------------------------------
__global__ __launch_bounds__(256) void attn_pv(
    const float* __restrict__ Q, const float* __restrict__ Kmat,
    const float* __restrict__ V,
    const float* __restrict__ rowmax, const float* __restrict__ rowsum,
    float* __restrict__ wout, float* __restrict__ aout)
{
    __shared__ float Qs[64][64];   // [d][r]
    __shared__ float U[64][64];    // K tile [d][c] during scores; P^T [k][r] during PV
    __shared__ float Vs[64][64];   // [kk][dd]

    const int qt = blockIdx.x;
    const int bh = blockIdx.y;
    const float* Qb = Q + ((size_t)bh * 2048 + qt * 64) * 64;
    const float* Kb = Kmat + (size_t)bh * 2048 * 64;
    const float* Vb = V + (size_t)bh * 2048 * 64;
    const int tid = threadIdx.x;

#pragma unroll
    for (int l = 0; l < 4; ++l) {
        int idx = tid + l * 256;
        int r = idx >> 4;
        int d0 = (idx & 15) * 4;
        float4 v = *(const float4*)(Qb + (size_t)r * 64 + d0);
        Qs[d0 + 0][r] = v.x; Qs[d0 + 1][r] = v.y;
        Qs[d0 + 2][r] = v.z; Qs[d0 + 3][r] = v.w;
    }

    const int ty = tid >> 4, tx = tid & 15;
    const int r0 = ty * 4, c0 = tx * 4;

    float M[4], Li[4];
#pragma unroll
    for (int i = 0; i < 4; ++i) {
        size_t r = (size_t)bh * 2048 + qt * 64 + r0 + i;
        M[i] = rowmax[r];
        Li[i] = 1.0f / rowsum[r];
    }

    float accO[4][4];
#pragma unroll
    for (int i = 0; i < 4; ++i)
#pragma unroll
        for (int j = 0; j < 4; ++j) accO[i][j] = 0.0f;

    for (int kt = 0; kt < 32; ++kt) {
        __syncthreads();   // prev PV done reading U (as P^T) and Vs
#pragma unroll
        for (int l = 0; l < 4; ++l) {
            int idx = tid + l * 256;
            int c = idx >> 4;
            int d0 = (idx & 15) * 4;
            float4 kv = *(const float4*)(Kb + ((size_t)kt * 64 + c) * 64 + d0);
            U[d0 + 0][c] = kv.x; U[d0 + 1][c] = kv.y;
            U[d0 + 2][c] = kv.z; U[d0 + 3][c] = kv.w;
            float4 vv = *(const float4*)(Vb + ((size_t)kt * 64 + c) * 64 + d0);
            *(float4*)&Vs[c][d0] = vv;
        }
        __syncthreads();

        // Scores 64x64: micro 4x4 (same d-summation order as pass 1)
        float s[4][4];
#pragma unroll
        for (int i = 0; i < 4; ++i)
#pragma unroll
            for (int j = 0; j < 4; ++j) s[i][j] = 0.0f;

        for (int d = 0; d < 64; ++d) {
            float a[4], b[4];
            *(float4*)(a) = *(const float4*)&Qs[d][r0];
            *(float4*)(b) = *(const float4*)&U[d][c0];
#pragma unroll
            for (int i = 0; i < 4; ++i)
#pragma unroll
                for (int j = 0; j < 4; ++j)
                    s[i][j] = fmaf(a[i], b[j], s[i][j]);
        }

        __syncthreads();   // everyone done reading U as the K tile

        // Normalize, write weights, stash P^T into U for the PV GEMM
#pragma unroll
        for (int i = 0; i < 4; ++i) {
            float w[4];
#pragma unroll
            for (int j = 0; j < 4; ++j)
                w[j] = __expf(s[i][j] * 0.125f - M[i]) * Li[i];
            size_t off = ((size_t)bh * 2048 + qt * 64 + r0 + i) * 2048
                       + (size_t)kt * 64 + c0;
            *(float4*)(wout + off) = *(const float4*)w;
#pragma unroll
            for (int j = 0; j < 4; ++j) U[c0 + j][r0 + i] = w[j];
        }
        __syncthreads();

        // O += P.V
        for (int kk = 0; kk < 64; ++kk) {
            float p[4], v[4];
            *(float4*)(p) = *(const float4*)&U[kk][r0];
            *(float4*)(v) = *(const float4*)&Vs[kk][tx * 4];
#pragma unroll
            for (int i = 0; i < 4; ++i)
#pragma unroll
                for (int j = 0; j < 4; ++j)
                    accO[i][j] = fmaf(p[i], v[j], accO[i][j]);
        }
    }

#pragma unroll
    for (int i = 0; i < 4; ++i) {
        float* dst = aout + ((size_t)bh * 2048 + qt * 64 + r0 + i) * 64 + tx * 4;
        *(float4*)dst = *(const float4*)&accO[i][0];
    }
}

// ---------------------------------------------------------------------------
extern "C" void kernel_launch(void* const* d_in, const int* in_sizes, int n_in,
                              void* d_out, int out_size, void* d_ws, size_t ws_size,
                              hipStream_t stream) {
    const float* x  = (const float*)d_in[0];
    const float* Wq = (const float*)d_in[1];
    const float* Wk = (const float*)d_in[2];
    const float* Wv = (const float*)d_in[3];
    const float* Wo = (const float*)d_in[4];

    float* out0 = (float*)d_out;                       // [2,2048,1024]
    float* out1 = out0 + (size_t)MTOT * DM;            // attn_weights [2,16,2048,2048]

    float* ws   = (float*)d_ws;                        // 64.5 MB used
    float* Qm   = ws;                                  // [B,H,T,64]
    float* Km   = Qm + (size_t)4194304;
    float* Vm   = Km + (size_t)4194304;
    float* AO   = Vm + (size_t)4194304;                // attn_out [B,H,T,64]
    float* rmax = AO + (size_t)4194304;                // [32*2048]
    float* rsum = rmax + (size_t)65536;

    dim3 blk(256);
    dim3 gg(32, 8);
    gemm_bt_x3<<<gg, blk, 0, stream>>>(x, Wq, Qm, 0);
    gemm_bt_x3<<<gg, blk, 0, stream>>>(x, Wk, Km, 0);
    gemm_bt_x3<<<gg, blk, 0, stream>>>(x, Wv, Vm, 0);

    dim3 ga(32, 32);
    rowstats<<<ga, blk, 0, stream>>>(Qm, Km, rmax, rsum);
    attn_pv<<<ga, blk, 0, stream>>>(Qm, Km, Vm, rmax, rsum, out1, AO);

    gemm_bt_x3<<<gg, blk, 0, stream>>>(AO, Wo, out0, 1);
}

// Round 2
// 1129.982 us; speedup vs baseline: 1.9199x; 1.3247x over previous
//
#include <hip/hip_runtime.h>
#include <math.h>

// Problem constants
#define BB 2
#define TT 2048
#define DM 1024
#define NH 16
#define DKK 64
#define MTOT (BB*TT)        // 4096
#define BHN (BB*NH)         // 32

typedef short bf16x8 __attribute__((ext_vector_type(8)));
typedef float f32x4 __attribute__((ext_vector_type(4)));

static __device__ __forceinline__ unsigned short f32_bf16(float f) {
    union { float f; unsigned u; } v; v.f = f;
    unsigned u = v.u + 0x7fffu + ((v.u >> 16) & 1u);   // RNE
    return (unsigned short)(u >> 16);
}
static __device__ __forceinline__ float bf16_f32(unsigned short h) {
    union { unsigned u; float f; } v; v.u = (unsigned)h << 16;
    return v.f;
}
static __device__ __forceinline__ void split4(float4 v, ushort4* h, ushort4* l) {
    h->x = f32_bf16(v.x); l->x = f32_bf16(v.x - bf16_f32(h->x));
    h->y = f32_bf16(v.y); l->y = f32_bf16(v.y - bf16_f32(h->y));
    h->z = f32_bf16(v.z); l->z = f32_bf16(v.z - bf16_f32(h->z));
    h->w = f32_bf16(v.w); l->w = f32_bf16(v.w - bf16_f32(h->w));
}
static __device__ __forceinline__ void split8(const float* a, bf16x8* h, bf16x8* l) {
#pragma unroll
    for (int e = 0; e < 8; ++e) {
        unsigned short hi = f32_bf16(a[e]);
        (*h)[e] = (short)hi;
        (*l)[e] = (short)f32_bf16(a[e] - bf16_f32(hi));
    }
}

// A addressing: mode 1 = gather from [B,H,T,64]; else plain row-major [M][K]
static __device__ __forceinline__ const float* aptr(const float* A, int mode, int m, int k) {
    if (mode != 1) return A + (size_t)m * 1024 + k;
    int b = m >> 11, t = m & 2047;
    int h = k >> 6, d = k & 63;
    return A + (((size_t)(b * 16 + h)) * 2048 + t) * 64 + d;
}

// ---------------------------------------------------------------------------
// C = A(4096x1024) * Bt(1024x1024)^T via bf16x3 (split-precision) MFMA.
// mode 0: C scattered to QKV layout [B,H,T,64]
// mode 1: A gathered from [B,H,T,64]; C plain [M][N]
// mode 2: C scattered to head-transposed layout [B,H,64,T]  (for V)
// ---------------------------------------------------------------------------
__global__ __launch_bounds__(256) void gemm_bt_x3(
    const float* __restrict__ A, const float* __restrict__ Bt,
    float* __restrict__ C, int mode)
{
    __shared__ __align__(16) unsigned short Ah[128*32];
    __shared__ __align__(16) unsigned short Al[128*32];
    __shared__ __align__(16) unsigned short Bh[128*32];
    __shared__ __align__(16) unsigned short Bl[128*32];

    const int tid = threadIdx.x;
    const int m_base = blockIdx.x * 128;
    const int n_base = blockIdx.y * 128;
    const int lane = tid & 63;
    const int wave = tid >> 6;
    const int wr = wave >> 1, wc = wave & 1;     // 64x64 quadrant
    const int l16 = lane & 15, lk = lane >> 4;

    f32x4 zero = {0.f, 0.f, 0.f, 0.f};
    f32x4 acc[4][4];
#pragma unroll
    for (int i = 0; i < 4; ++i)
#pragma unroll
        for (int j = 0; j < 4; ++j) acc[i][j] = zero;

    float4 ga[4], gb[4];
#pragma unroll
    for (int q = 0; q < 4; ++q) {
        int fq = tid + q * 256;
        int row = fq >> 3, kq = fq & 7;
        ga[q] = *(const float4*)aptr(A, mode, m_base + row, kq * 4);
        gb[q] = *(const float4*)(Bt + (size_t)(n_base + row) * 1024 + kq * 4);
    }

    for (int ks = 0; ks < 32; ++ks) {
        __syncthreads();
#pragma unroll
        for (int q = 0; q < 4; ++q) {
            int fq = tid + q * 256;
            int row = fq >> 3, kq = fq & 7;
            int sw = (kq >> 1) ^ ((row >> 1) & 3);
            int base = row * 32 + sw * 8 + (kq & 1) * 4;
            ushort4 h, l;
            split4(ga[q], &h, &l);
            *(ushort4*)&Ah[base] = h;
            *(ushort4*)&Al[base] = l;
            split4(gb[q], &h, &l);
            *(ushort4*)&Bh[base] = h;
            *(ushort4*)&Bl[base] = l;
        }
        __syncthreads();

        if (ks + 1 < 32) {
            int k0 = (ks + 1) * 32;
#pragma unroll
            for (int q = 0; q < 4; ++q) {
                int fq = tid + q * 256;
                int row = fq >> 3, kq = fq & 7;
                ga[q] = *(const float4*)aptr(A, mode, m_base + row, k0 + kq * 4);
                gb[q] = *(const float4*)(Bt + (size_t)(n_base + row) * 1024 + k0 + kq * 4);
            }
        }

        bf16x8 fah[4], fal[4], fbh[4], fbl[4];
#pragma unroll
        for (int i = 0; i < 4; ++i) {
            int am = wr * 64 + i * 16 + l16;
            int ao = am * 32 + ((lk ^ ((am >> 1) & 3)) * 8);
            fah[i] = *(const bf16x8*)&Ah[ao];
            fal[i] = *(const bf16x8*)&Al[ao];
            int bn = wc * 64 + i * 16 + l16;
            int bo = bn * 32 + ((lk ^ ((bn >> 1) & 3)) * 8);
            fbh[i] = *(const bf16x8*)&Bh[bo];
            fbl[i] = *(const bf16x8*)&Bl[bo];
        }
#pragma unroll
        for (int i = 0; i < 4; ++i)
#pragma unroll
            for (int j = 0; j < 4; ++j) {
                acc[i][j] = __builtin_amdgcn_mfma_f32_16x16x32_bf16(fah[i], fbh[j], acc[i][j], 0, 0, 0);
                acc[i][j] = __builtin_amdgcn_mfma_f32_16x16x32_bf16(fah[i], fbl[j], acc[i][j], 0, 0, 0);
                acc[i][j] = __builtin_amdgcn_mfma_f32_16x16x32_bf16(fal[i], fbh[j], acc[i][j], 0, 0, 0);
            }
    }

    // C/D layout (verified): col = lane&15, row = (lane>>4)*4 + reg
#pragma unroll
    for (int i = 0; i < 4; ++i) {
#pragma unroll
        for (int j = 0; j < 4; ++j) {
            int gn = n_base + wc * 64 + j * 16 + l16;
#pragma unroll
            for (int r = 0; r < 4; ++r) {
                int gm = m_base + wr * 64 + i * 16 + lk * 4 + r;
                float val = acc[i][j][r];
                if (mode == 0) {
                    int b = gm >> 11, t = gm & 2047;
                    int h = gn >> 6, d = gn & 63;
                    C[(((size_t)(b * 16 + h)) * 2048 + t) * 64 + d] = val;
                } else if (mode == 2) {
                    int b = gm >> 11, t = gm & 2047;
                    int h = gn >> 6, d = gn & 63;
                    C[(((size_t)(b * 16 + h)) * 64 + d) * 2048 + t] = val;
                } else {
                    C[(size_t)gm * 1024 + gn] = val;
                }
            }
        }
    }
}

// ---------------------------------------------------------------------------
// Pass 1: per (bh, 64-row q tile), stream all 2048 k-cols via bf16x3 MFMA,
// tracking per-lane online (max, sumexp); one cross-lane merge at the end.
// QK^T code is textually identical to pass 2 -> bit-identical scores.
// ---------------------------------------------------------------------------
__global__ __launch_bounds__(256) void rowstats(
    const float* __restrict__ Q, const float* __restrict__ Kmat,
    float* __restrict__ rowmax, float* __restrict__ rowsum)
{
    __shared__ __align__(16) unsigned short Kh[64*64];
    __shared__ __align__(16) unsigned short Kl[64*64];

    const int qt = blockIdx.x, bh = blockIdx.y;
    const int tid = threadIdx.x;
    const int lane = tid & 63, wave = tid >> 6;
    const int l16 = lane & 15, lk = lane >> 4;

    // Q fragments in registers: wave's rows = qt*64 + wave*16 + (0..15)
    const float* Qrow = Q + ((size_t)(bh * 2048 + qt * 64 + wave * 16 + l16)) * 64;
    bf16x8 qh[2], ql[2];
#pragma unroll
    for (int c = 0; c < 2; ++c) {
        float a[8];
        *(float4*)(a)     = *(const float4*)(Qrow + c * 32 + lk * 8);
        *(float4*)(a + 4) = *(const float4*)(Qrow + c * 32 + lk * 8 + 4);
        split8(a, &qh[c], &ql[c]);
    }

    const float* Kb = Kmat + (size_t)bh * 2048 * 64;

    float mrow[4], lrow[4];
#pragma unroll
    for (int r = 0; r < 4; ++r) { mrow[r] = -INFINITY; lrow[r] = 0.0f; }

    for (int kt = 0; kt < 32; ++kt) {
        __syncthreads();
        // stage K tile (64 cols x 64 d) as hi/lo bf16, XOR-swizzled
#pragma unroll
        for (int l = 0; l < 4; ++l) {
            int idx = tid + l * 256;
            int col = idx >> 4, d0 = (idx & 15) * 4;
            float4 v = *(const float4*)(Kb + ((size_t)(kt * 64 + col)) * 64 + d0);
            ushort4 h, lo;
            split4(v, &h, &lo);
            int byte = (col * 128 + d0 * 2) ^ ((col & 7) << 4);
            *(ushort4*)((char*)Kh + byte) = h;
            *(ushort4*)((char*)Kl + byte) = lo;
        }
        __syncthreads();

        f32x4 s[4];
#pragma unroll
        for (int j = 0; j < 4; ++j) {
            s[j] = (f32x4){0.f, 0.f, 0.f, 0.f};
            int col = j * 16 + l16;
#pragma unroll
            for (int c = 0; c < 2; ++c) {
                int byte = (col * 128 + c * 64 + lk * 16) ^ ((col & 7) << 4);
                bf16x8 kh = *(const bf16x8*)((const char*)Kh + byte);
                bf16x8 kl = *(const bf16x8*)((const char*)Kl + byte);
                s[j] = __builtin_amdgcn_mfma_f32_16x16x32_bf16(qh[c], kh, s[j], 0, 0, 0);
                s[j] = __builtin_amdgcn_mfma_f32_16x16x32_bf16(qh[c], kl, s[j], 0, 0, 0);
                s[j] = __builtin_amdgcn_mfma_f32_16x16x32_bf16(ql[c], kh, s[j], 0, 0, 0);
            }
        }

        // online stats; S row = lk*4 + r (local), col = j*16 + l16
#pragma unroll
        for (int r = 0; r < 4; ++r) {
            float sc[4];
#pragma unroll
            for (int j = 0; j < 4; ++j) sc[j] = s[j][r] * 0.125f;
            float mx = fmaxf(fmaxf(sc[0], sc[1]), fmaxf(sc[2], sc[3]));
            float mnew = fmaxf(mrow[r], mx);
            float ls = __expf(sc[0] - mnew) + __expf(sc[1] - mnew)
                     + __expf(sc[2] - mnew) + __expf(sc[3] - mnew);
            lrow[r] = lrow[r] * __expf(mrow[r] - mnew) + ls;
            mrow[r] = mnew;
        }
    }

    // merge across the 16 col-lanes (same lk group)
#pragma unroll
    for (int off = 1; off < 16; off <<= 1) {
#pragma unroll
        for (int r = 0; r < 4; ++r) {
            float mo = __shfl_xor(mrow[r], off);
            float lo = __shfl_xor(lrow[r], off);
            float mn = fmaxf(mrow[r], mo);
            lrow[r] = lrow[r] * __expf(mrow[r] - mn) + lo * __expf(mo - mn);
            mrow[r] = mn;
        }
    }
    if (l16 == 0) {
#pragma unroll
        for (int r = 0; r < 4; ++r) {
            int row = qt * 64 + wave * 16 + lk * 4 + r;
            rowmax[(size_t)bh * 2048 + row] = mrow[r];
            rowsum[(size_t)bh * 2048 + row] = lrow[r];
        }
    }
}

// ---------------------------------------------------------------------------
// Pass 2: recompute scores (bit-identical MFMA path), normalize with
// (rowmax,rowsum), stash normalized P in swizzled LDS (fp32), then
// (a) coalesced float4 attn_weights stores, (b) bf16x3 MFMA PV from P and
// V^T (staged from the head-transposed V produced by gemm mode 2).
// LDS = 48 KiB -> 3 blocks/CU.
// ---------------------------------------------------------------------------
__global__ __launch_bounds__(256) void attn_pv(
    const float* __restrict__ Q, const float* __restrict__ Kmat,
    const float* __restrict__ VT,
    const float* __restrict__ rowmax, const float* __restrict__ rowsum,
    float* __restrict__ wout, float* __restrict__ aout)
{
    __shared__ __align__(16) unsigned short Kh[64*64];
    __shared__ __align__(16) unsigned short Kl[64*64];
    __shared__ __align__(16) unsigned short Vh[64*64];
    __shared__ __align__(16) unsigned short Vl[64*64];
    __shared__ __align__(16) float Ps[64*64];

    const int qt = blockIdx.x, bh = blockIdx.y;
    const int tid = threadIdx.x;
    const int lane = tid & 63, wave = tid >> 6;
    const int l16 = lane & 15, lk = lane >> 4;

    const float* Qrow = Q + ((size_t)(bh * 2048 + qt * 64 + wave * 16 + l16)) * 64;
    bf16x8 qh[2], ql[2];
#pragma unroll
    for (int c = 0; c < 2; ++c) {
        float a[8];
        *(float4*)(a)     = *(const float4*)(Qrow + c * 32 + lk * 8);
        *(float4*)(a + 4) = *(const float4*)(Qrow + c * 32 + lk * 8 + 4);
        split8(a, &qh[c], &ql[c]);
    }

    const float* Kb = Kmat + (size_t)bh * 2048 * 64;
    const float* Vb = VT + (size_t)bh * 64 * 2048;

    float M[4], Li[4];
#pragma unroll
    for (int r = 0; r < 4; ++r) {
        int row = qt * 64 + wave * 16 + lk * 4 + r;
        M[r]  = rowmax[(size_t)bh * 2048 + row];
        Li[r] = 1.0f / rowsum[(size_t)bh * 2048 + row];
    }

    f32x4 accO[4];
#pragma unroll
    for (int j = 0; j < 4; ++j) accO[j] = (f32x4){0.f, 0.f, 0.f, 0.f};

    for (int kt = 0; kt < 32; ++kt) {
        __syncthreads();
        // stage K tile (identical to pass 1)
#pragma unroll
        for (int l = 0; l < 4; ++l) {
            int idx = tid + l * 256;
            int col = idx >> 4, d0 = (idx & 15) * 4;
            float4 v = *(const float4*)(Kb + ((size_t)(kt * 64 + col)) * 64 + d0);
            ushort4 h, lo;
            split4(v, &h, &lo);
            int byte = (col * 128 + d0 * 2) ^ ((col & 7) << 4);
            *(ushort4*)((char*)Kh + byte) = h;
            *(ushort4*)((char*)Kl + byte) = lo;
        }
        // stage V^T tile: rows d (64), cols k (64), coalesced from [bh][d][t]
#pragma unroll
        for (int l = 0; l < 4; ++l) {
            int idx = tid + l * 256;
            int d = idx >> 4, kq = idx & 15;
            float4 v = *(const float4*)(Vb + (size_t)d * 2048 + kt * 64 + kq * 4);
            ushort4 h, lo;
            split4(v, &h, &lo);
            int byte = (d * 128 + kq * 8) ^ ((d & 7) << 4);
            *(ushort4*)((char*)Vh + byte) = h;
            *(ushort4*)((char*)Vl + byte) = lo;
        }
        __syncthreads();

        f32x4 s[4];
#pragma unroll
        for (int j = 0; j < 4; ++j) {
            s[j] = (f32x4){0.f, 0.f, 0.f, 0.f};
            int col = j * 16 + l16;
#pragma unroll
            for (int c = 0; c < 2; ++c) {
                int byte = (col * 128 + c * 64 + lk * 16) ^ ((col & 7) << 4);
                bf16x8 kh = *(const bf16x8*)((const char*)Kh + byte);
                bf16x8 kl = *(const bf16x8*)((const char*)Kl + byte);
                s[j] = __builtin_amdgcn_mfma_f32_16x16x32_bf16(qh[c], kh, s[j], 0, 0, 0);
                s[j] = __builtin_amdgcn_mfma_f32_16x16x32_bf16(qh[c], kl, s[j], 0, 0, 0);
                s[j] = __builtin_amdgcn_mfma_f32_16x16x32_bf16(ql[c], kh, s[j], 0, 0, 0);
            }
        }

        // normalize -> Ps (fp32, swizzled). S row = lk*4+r, col = j*16+l16
#pragma unroll
        for (int j = 0; j < 4; ++j) {
            int col = j * 16 + l16;
#pragma unroll
            for (int r = 0; r < 4; ++r) {
                int qrow = wave * 16 + lk * 4 + r;
                float w = __expf(s[j][r] * 0.125f - M[r]) * Li[r];
                int byte = (qrow * 256 + col * 4) ^ ((qrow & 7) << 4);
                *(float*)((char*)Ps + byte) = w;
            }
        }
        __syncthreads();

        // attn_weights: coalesced float4 stores from Ps
        size_t wbase = ((size_t)bh * 2048 + qt * 64) * 2048 + (size_t)kt * 64;
#pragma unroll
        for (int l = 0; l < 4; ++l) {
            int idx = tid + l * 256;
            int q = idx >> 4, kq = idx & 15;
            int byte = (q * 256 + kq * 16) ^ ((q & 7) << 4);
            float4 v = *(const float4*)((const char*)Ps + byte);
            *(float4*)(wout + wbase + (size_t)q * 2048 + kq * 4) = v;
        }

        // PV: A = P (wave's 16 rows), B = V^T; bf16x3
#pragma unroll
        for (int c = 0; c < 2; ++c) {
            int qrow = wave * 16 + l16;
            int b0 = qrow * 256 + c * 128 + lk * 32;
            int swz = (qrow & 7) << 4;
            float p[8];
            *(float4*)(p)     = *(const float4*)((const char*)Ps + (b0 ^ swz));
            *(float4*)(p + 4) = *(const float4*)((const char*)Ps + ((b0 + 16) ^ swz));
            bf16x8 pah, pal;
            split8(p, &pah, &pal);
#pragma unroll
            for (int j = 0; j < 4; ++j) {
                int d = j * 16 + l16;
                int byte = (d * 128 + c * 64 + lk * 16) ^ ((d & 7) << 4);
                bf16x8 vh = *(const bf16x8*)((const char*)Vh + byte);
                bf16x8 vl = *(const bf16x8*)((const char*)Vl + byte);
                accO[j] = __builtin_amdgcn_mfma_f32_16x16x32_bf16(pah, vh, accO[j], 0, 0, 0);
                accO[j] = __builtin_amdgcn_mfma_f32_16x16x32_bf16(pah, vl, accO[j], 0, 0, 0);
                accO[j] = __builtin_amdgcn_mfma_f32_16x16x32_bf16(pal, vh, accO[j], 0, 0, 0);
            }
        }
    }

    // epilogue: AO [bh][t][64]; out row = lk*4+r, d = j*16+l16
#pragma unroll
    for (int j = 0; j < 4; ++j) {
        int d = j * 16 + l16;
#pragma unroll
        for (int r = 0; r < 4; ++r) {
            int row = qt * 64 + wave * 16 + lk * 4 + r;
            aout[((size_t)bh * 2048 + row) * 64 + d] = accO[j][r];
        }
    }
}

// ---------------------------------------------------------------------------
extern "C" void kernel_launch(void* const* d_in, const int* in_sizes, int n_in,
                              void* d_out, int out_size, void* d_ws, size_t ws_size,
                              hipStream_t stream) {
    const float* x  = (const float*)d_in[0];
    const float* Wq = (const float*)d_in[1];
    const float* Wk = (const float*)d_in[2];
    const float* Wv = (const float*)d_in[3];
    const float* Wo = (const float*)d_in[4];

    float* out0 = (float*)d_out;                       // [2,2048,1024]
    float* out1 = out0 + (size_t)MTOT * DM;            // attn_weights [2,16,2048,2048]

    float* ws   = (float*)d_ws;
    float* Qm   = ws;                                  // [B,H,T,64]
    float* Km   = Qm + (size_t)4194304;                // [B,H,T,64]
    float* VT   = Km + (size_t)4194304;                // [B,H,64,T]  (head-transposed V)
    float* AO   = VT + (size_t)4194304;                // attn_out [B,H,T,64]
    float* rmax = AO + (size_t)4194304;                // [32*2048]
    float* rsum = rmax + (size_t)65536;

    dim3 blk(256);
    dim3 gg(32, 8);
    gemm_bt_x3<<<gg, blk, 0, stream>>>(x, Wq, Qm, 0);
    gemm_bt_x3<<<gg, blk, 0, stream>>>(x, Wk, Km, 0);
    gemm_bt_x3<<<gg, blk, 0, stream>>>(x, Wv, VT, 2);

    dim3 ga(32, 32);
    rowstats<<<ga, blk, 0, stream>>>(Qm, Km, rmax, rsum);
    attn_pv<<<ga, blk, 0, stream>>>(Qm, Km, VT, rmax, rsum, out1, AO);

    gemm_bt_x3<<<gg, blk, 0, stream>>>(AO, Wo, out0, 1);
}

// Round 4
// 926.303 us; speedup vs baseline: 2.3421x; 1.2199x over previous
//
#include <hip/hip_runtime.h>
#include <math.h>

// Problem constants
#define BB 2
#define TT 2048
#define DM 1024
#define NH 16
#define DKK 64
#define MTOT (BB*TT)        // 4096
#define BHN (BB*NH)         // 32

typedef short bf16x8 __attribute__((ext_vector_type(8)));
typedef float f32x4 __attribute__((ext_vector_type(4)));

static __device__ __forceinline__ unsigned short f32_bf16(float f) {
    union { float f; unsigned u; } v; v.f = f;
    unsigned u = v.u + 0x7fffu + ((v.u >> 16) & 1u);   // RNE
    return (unsigned short)(u >> 16);
}
static __device__ __forceinline__ float bf16_f32(unsigned short h) {
    union { unsigned u; float f; } v; v.u = (unsigned)h << 16;
    return v.f;
}
static __device__ __forceinline__ void split4(float4 v, ushort4* h, ushort4* l) {
    h->x = f32_bf16(v.x); l->x = f32_bf16(v.x - bf16_f32(h->x));
    h->y = f32_bf16(v.y); l->y = f32_bf16(v.y - bf16_f32(h->y));
    h->z = f32_bf16(v.z); l->z = f32_bf16(v.z - bf16_f32(h->z));
    h->w = f32_bf16(v.w); l->w = f32_bf16(v.w - bf16_f32(h->w));
}
static __device__ __forceinline__ void split8(const float* a, bf16x8* h, bf16x8* l) {
#pragma unroll
    for (int e = 0; e < 8; ++e) {
        unsigned short hi = f32_bf16(a[e]);
        (*h)[e] = (short)hi;
        (*l)[e] = (short)f32_bf16(a[e] - bf16_f32(hi));
    }
}

// A addressing: mode 1 = gather from [B,H,T,64]; else plain row-major [M][K]
static __device__ __forceinline__ const float* aptr(const float* A, int mode, int m, int k) {
    if (mode != 1) return A + (size_t)m * 1024 + k;
    int b = m >> 11, t = m & 2047;
    int h = k >> 6, d = k & 63;
    return A + (((size_t)(b * 16 + h)) * 2048 + t) * 64 + d;
}

// ---------------------------------------------------------------------------
// C = A(4096x1024) * Bt(1024x1024)^T via bf16x3 (split-precision) MFMA.
// mode 0: C scattered to QKV layout [B,H,T,64]
// mode 1: A gathered from [B,H,T,64]; C plain [M][N]
// mode 2: C scattered to head-transposed layout [B,H,64,T]  (for V)
// ---------------------------------------------------------------------------
__global__ __launch_bounds__(256) void gemm_bt_x3(
    const float* __restrict__ A, const float* __restrict__ Bt,
    float* __restrict__ C, int mode)
{
    __shared__ __align__(16) unsigned short Ah[128*32];
    __shared__ __align__(16) unsigned short Al[128*32];
    __shared__ __align__(16) unsigned short Bh[128*32];
    __shared__ __align__(16) unsigned short Bl[128*32];

    const int tid = threadIdx.x;
    const int m_base = blockIdx.x * 128;
    const int n_base = blockIdx.y * 128;
    const int lane = tid & 63;
    const int wave = tid >> 6;
    const int wr = wave >> 1, wc = wave & 1;     // 64x64 quadrant
    const int l16 = lane & 15, lk = lane >> 4;

    f32x4 zero = {0.f, 0.f, 0.f, 0.f};
    f32x4 acc[4][4];
#pragma unroll
    for (int i = 0; i < 4; ++i)
#pragma unroll
        for (int j = 0; j < 4; ++j) acc[i][j] = zero;

    float4 ga[4], gb[4];
#pragma unroll
    for (int q = 0; q < 4; ++q) {
        int fq = tid + q * 256;
        int row = fq >> 3, kq = fq & 7;
        ga[q] = *(const float4*)aptr(A, mode, m_base + row, kq * 4);
        gb[q] = *(const float4*)(Bt + (size_t)(n_base + row) * 1024 + kq * 4);
    }

    for (int ks = 0; ks < 32; ++ks) {
        __syncthreads();
#pragma unroll
        for (int q = 0; q < 4; ++q) {
            int fq = tid + q * 256;
            int row = fq >> 3, kq = fq & 7;
            int sw = (kq >> 1) ^ ((row >> 1) & 3);
            int base = row * 32 + sw * 8 + (kq & 1) * 4;
            ushort4 h, l;
            split4(ga[q], &h, &l);
            *(ushort4*)&Ah[base] = h;
            *(ushort4*)&Al[base] = l;
            split4(gb[q], &h, &l);
            *(ushort4*)&Bh[base] = h;
            *(ushort4*)&Bl[base] = l;
        }
        __syncthreads();

        if (ks + 1 < 32) {
            int k0 = (ks + 1) * 32;
#pragma unroll
            for (int q = 0; q < 4; ++q) {
                int fq = tid + q * 256;
                int row = fq >> 3, kq = fq & 7;
                ga[q] = *(const float4*)aptr(A, mode, m_base + row, k0 + kq * 4);
                gb[q] = *(const float4*)(Bt + (size_t)(n_base + row) * 1024 + k0 + kq * 4);
            }
        }

        bf16x8 fah[4], fal[4], fbh[4], fbl[4];
#pragma unroll
        for (int i = 0; i < 4; ++i) {
            int am = wr * 64 + i * 16 + l16;
            int ao = am * 32 + ((lk ^ ((am >> 1) & 3)) * 8);
            fah[i] = *(const bf16x8*)&Ah[ao];
            fal[i] = *(const bf16x8*)&Al[ao];
            int bn = wc * 64 + i * 16 + l16;
            int bo = bn * 32 + ((lk ^ ((bn >> 1) & 3)) * 8);
            fbh[i] = *(const bf16x8*)&Bh[bo];
            fbl[i] = *(const bf16x8*)&Bl[bo];
        }
        __builtin_amdgcn_s_setprio(1);
#pragma unroll
        for (int i = 0; i < 4; ++i)
#pragma unroll
            for (int j = 0; j < 4; ++j) {
                acc[i][j] = __builtin_amdgcn_mfma_f32_16x16x32_bf16(fah[i], fbh[j], acc[i][j], 0, 0, 0);
                acc[i][j] = __builtin_amdgcn_mfma_f32_16x16x32_bf16(fah[i], fbl[j], acc[i][j], 0, 0, 0);
                acc[i][j] = __builtin_amdgcn_mfma_f32_16x16x32_bf16(fal[i], fbh[j], acc[i][j], 0, 0, 0);
            }
        __builtin_amdgcn_s_setprio(0);
    }

    // C/D layout (verified): col = lane&15, row = (lane>>4)*4 + reg
#pragma unroll
    for (int i = 0; i < 4; ++i) {
#pragma unroll
        for (int j = 0; j < 4; ++j) {
            int gn = n_base + wc * 64 + j * 16 + l16;
#pragma unroll
            for (int r = 0; r < 4; ++r) {
                int gm = m_base + wr * 64 + i * 16 + lk * 4 + r;
                float val = acc[i][j][r];
                if (mode == 0) {
                    int b = gm >> 11, t = gm & 2047;
                    int h = gn >> 6, d = gn & 63;
                    C[(((size_t)(b * 16 + h)) * 2048 + t) * 64 + d] = val;
                } else if (mode == 2) {
                    int b = gm >> 11, t = gm & 2047;
                    int h = gn >> 6, d = gn & 63;
                    C[(((size_t)(b * 16 + h)) * 64 + d) * 2048 + t] = val;
                } else {
                    C[(size_t)gm * 1024 + gn] = val;
                }
            }
        }
    }
}

// ---------------------------------------------------------------------------
// Pass 1: per (bh, 64-row q tile), stream all 2048 k-cols via bf16x3 MFMA,
// tracking per-lane online (max, sumexp). Register-prefetch of the next
// K tile hides global latency under the MFMA+stats phase.
// QK^T code is textually identical to pass 2 -> bit-identical scores.
// ---------------------------------------------------------------------------
__global__ __launch_bounds__(256) void rowstats(
    const float* __restrict__ Q, const float* __restrict__ Kmat,
    float* __restrict__ rowmax, float* __restrict__ rowsum)
{
    __shared__ __align__(16) unsigned short Kh[64*64];
    __shared__ __align__(16) unsigned short Kl[64*64];

    const int qt = blockIdx.x, bh = blockIdx.y;
    const int tid = threadIdx.x;
    const int lane = tid & 63, wave = tid >> 6;
    const int l16 = lane & 15, lk = lane >> 4;

    const float* Qrow = Q + ((size_t)(bh * 2048 + qt * 64 + wave * 16 + l16)) * 64;
    bf16x8 qh[2], ql[2];
#pragma unroll
    for (int c = 0; c < 2; ++c) {
        float a[8];
        *(float4*)(a)     = *(const float4*)(Qrow + c * 32 + lk * 8);
        *(float4*)(a + 4) = *(const float4*)(Qrow + c * 32 + lk * 8 + 4);
        split8(a, &qh[c], &ql[c]);
    }

    const float* Kb = Kmat + (size_t)bh * 2048 * 64;

    float mrow[4], lrow[4];
#pragma unroll
    for (int r = 0; r < 4; ++r) { mrow[r] = -INFINITY; lrow[r] = 0.0f; }

    // prefetch tile 0
    float4 pk[4];
#pragma unroll
    for (int l = 0; l < 4; ++l) {
        int idx = tid + l * 256;
        int col = idx >> 4, d0 = (idx & 15) * 4;
        pk[l] = *(const float4*)(Kb + (size_t)col * 64 + d0);
    }

    for (int kt = 0; kt < 32; ++kt) {
        __syncthreads();
        // stage prefetched K tile as hi/lo bf16, XOR-swizzled
#pragma unroll
        for (int l = 0; l < 4; ++l) {
            int idx = tid + l * 256;
            int col = idx >> 4, d0 = (idx & 15) * 4;
            ushort4 h, lo;
            split4(pk[l], &h, &lo);
            int byte = (col * 128 + d0 * 2) ^ ((col & 7) << 4);
            *(ushort4*)((char*)Kh + byte) = h;
            *(ushort4*)((char*)Kl + byte) = lo;
        }
        __syncthreads();

        // issue next tile's loads (latency hides under MFMA + stats)
        if (kt + 1 < 32) {
#pragma unroll
            for (int l = 0; l < 4; ++l) {
                int idx = tid + l * 256;
                int col = idx >> 4, d0 = (idx & 15) * 4;
                pk[l] = *(const float4*)(Kb + ((size_t)((kt + 1) * 64 + col)) * 64 + d0);
            }
        }

        f32x4 s[4];
        __builtin_amdgcn_s_setprio(1);
#pragma unroll
        for (int j = 0; j < 4; ++j) {
            s[j] = (f32x4){0.f, 0.f, 0.f, 0.f};
            int col = j * 16 + l16;
#pragma unroll
            for (int c = 0; c < 2; ++c) {
                int byte = (col * 128 + c * 64 + lk * 16) ^ ((col & 7) << 4);
                bf16x8 kh = *(const bf16x8*)((const char*)Kh + byte);
                bf16x8 kl = *(const bf16x8*)((const char*)Kl + byte);
                s[j] = __builtin_amdgcn_mfma_f32_16x16x32_bf16(qh[c], kh, s[j], 0, 0, 0);
                s[j] = __builtin_amdgcn_mfma_f32_16x16x32_bf16(qh[c], kl, s[j], 0, 0, 0);
                s[j] = __builtin_amdgcn_mfma_f32_16x16x32_bf16(ql[c], kh, s[j], 0, 0, 0);
            }
        }
        __builtin_amdgcn_s_setprio(0);

        // online stats; S row = lk*4 + r (local), col = j*16 + l16
#pragma unroll
        for (int r = 0; r < 4; ++r) {
            float sc[4];
#pragma unroll
            for (int j = 0; j < 4; ++j) sc[j] = s[j][r] * 0.125f;
            float mx = fmaxf(fmaxf(sc[0], sc[1]), fmaxf(sc[2], sc[3]));
            float mnew = fmaxf(mrow[r], mx);
            float ls = __expf(sc[0] - mnew) + __expf(sc[1] - mnew)
                     + __expf(sc[2] - mnew) + __expf(sc[3] - mnew);
            lrow[r] = lrow[r] * __expf(mrow[r] - mnew) + ls;
            mrow[r] = mnew;
        }
    }

    // merge across the 16 col-lanes
#pragma unroll
    for (int off = 1; off < 16; off <<= 1) {
#pragma unroll
        for (int r = 0; r < 4; ++r) {
            float mo = __shfl_xor(mrow[r], off);
            float lo = __shfl_xor(lrow[r], off);
            float mn = fmaxf(mrow[r], mo);
            lrow[r] = lrow[r] * __expf(mrow[r] - mn) + lo * __expf(mo - mn);
            mrow[r] = mn;
        }
    }
    if (l16 == 0) {
#pragma unroll
        for (int r = 0; r < 4; ++r) {
            int row = qt * 64 + wave * 16 + lk * 4 + r;
            rowmax[(size_t)bh * 2048 + row] = mrow[r];
            rowsum[(size_t)bh * 2048 + row] = lrow[r];
        }
    }
}

// ---------------------------------------------------------------------------
// Pass 2: recompute scores (bit-identical MFMA path), normalize, write
// attn_weights (wave-local, nontemporal), PV via bf16x3 MFMA.
// Register prefetch of next K/V tile; 3 barriers -> 2 (Ps is wave-local:
// lgkmcnt fence instead of s_barrier); setprio around MFMA; nontemporal
// attn_weights stores. LDS 48 KiB -> 3 blocks/CU.
// ---------------------------------------------------------------------------
__global__ __launch_bounds__(256) void attn_pv(
    const float* __restrict__ Q, const float* __restrict__ Kmat,
    const float* __restrict__ VT,
    const float* __restrict__ rowmax, const float* __restrict__ rowsum,
    float* __restrict__ wout, float* __restrict__ aout)
{
    __shared__ __align__(16) unsigned short Kh[64*64];
    __shared__ __align__(16) unsigned short Kl[64*64];
    __shared__ __align__(16) unsigned short Vh[64*64];
    __shared__ __align__(16) unsigned short Vl[64*64];
    __shared__ __align__(16) float Ps[64*64];

    const int qt = blockIdx.x, bh = blockIdx.y;
    const int tid = threadIdx.x;
    const int lane = tid & 63, wave = tid >> 6;
    const int l16 = lane & 15, lk = lane >> 4;

    const float* Qrow = Q + ((size_t)(bh * 2048 + qt * 64 + wave * 16 + l16)) * 64;
    bf16x8 qh[2], ql[2];
#pragma unroll
    for (int c = 0; c < 2; ++c) {
        float a[8];
        *(float4*)(a)     = *(const float4*)(Qrow + c * 32 + lk * 8);
        *(float4*)(a + 4) = *(const float4*)(Qrow + c * 32 + lk * 8 + 4);
        split8(a, &qh[c], &ql[c]);
    }

    const float* Kb = Kmat + (size_t)bh * 2048 * 64;
    const float* Vb = VT + (size_t)bh * 64 * 2048;

    float M[4], Li[4];
#pragma unroll
    for (int r = 0; r < 4; ++r) {
        int row = qt * 64 + wave * 16 + lk * 4 + r;
        M[r]  = rowmax[(size_t)bh * 2048 + row];
        Li[r] = 1.0f / rowsum[(size_t)bh * 2048 + row];
    }

    f32x4 accO[4];
#pragma unroll
    for (int j = 0; j < 4; ++j) accO[j] = (f32x4){0.f, 0.f, 0.f, 0.f};

    // prefetch tile 0 (K and V^T)
    float4 pk[4], pv[4];
#pragma unroll
    for (int l = 0; l < 4; ++l) {
        int idx = tid + l * 256;
        int col = idx >> 4, d0 = (idx & 15) * 4;
        pk[l] = *(const float4*)(Kb + (size_t)col * 64 + d0);
        pv[l] = *(const float4*)(Vb + (size_t)col * 2048 + (idx & 15) * 4);
    }

    for (int kt = 0; kt < 32; ++kt) {
        __syncthreads();   // prev tile's K/V LDS reads done
        // stage K tile
#pragma unroll
        for (int l = 0; l < 4; ++l) {
            int idx = tid + l * 256;
            int col = idx >> 4, d0 = (idx & 15) * 4;
            ushort4 h, lo;
            split4(pk[l], &h, &lo);
            int byte = (col * 128 + d0 * 2) ^ ((col & 7) << 4);
            *(ushort4*)((char*)Kh + byte) = h;
            *(ushort4*)((char*)Kl + byte) = lo;
        }
        // stage V^T tile
#pragma unroll
        for (int l = 0; l < 4; ++l) {
            int idx = tid + l * 256;
            int d = idx >> 4, kq = idx & 15;
            ushort4 h, lo;
            split4(pv[l], &h, &lo);
            int byte = (d * 128 + kq * 8) ^ ((d & 7) << 4);
            *(ushort4*)((char*)Vh + byte) = h;
            *(ushort4*)((char*)Vl + byte) = lo;
        }
        __syncthreads();

        // issue next tile's global loads; latency hides under QK^T+softmax+PV
        if (kt + 1 < 32) {
#pragma unroll
            for (int l = 0; l < 4; ++l) {
                int idx = tid + l * 256;
                int col = idx >> 4, d0 = (idx & 15) * 4;
                pk[l] = *(const float4*)(Kb + ((size_t)((kt + 1) * 64 + col)) * 64 + d0);
                pv[l] = *(const float4*)(Vb + (size_t)col * 2048 + (kt + 1) * 64 + (idx & 15) * 4);
            }
        }

        f32x4 s[4];
        __builtin_amdgcn_s_setprio(1);
#pragma unroll
        for (int j = 0; j < 4; ++j) {
            s[j] = (f32x4){0.f, 0.f, 0.f, 0.f};
            int col = j * 16 + l16;
#pragma unroll
            for (int c = 0; c < 2; ++c) {
                int byte = (col * 128 + c * 64 + lk * 16) ^ ((col & 7) << 4);
                bf16x8 kh = *(const bf16x8*)((const char*)Kh + byte);
                bf16x8 kl = *(const bf16x8*)((const char*)Kl + byte);
                s[j] = __builtin_amdgcn_mfma_f32_16x16x32_bf16(qh[c], kh, s[j], 0, 0, 0);
                s[j] = __builtin_amdgcn_mfma_f32_16x16x32_bf16(qh[c], kl, s[j], 0, 0, 0);
                s[j] = __builtin_amdgcn_mfma_f32_16x16x32_bf16(ql[c], kh, s[j], 0, 0, 0);
            }
        }
        __builtin_amdgcn_s_setprio(0);

        // normalize -> Ps (wave-local rows). S row = lk*4+r, col = j*16+l16
#pragma unroll
        for (int j = 0; j < 4; ++j) {
            int col = j * 16 + l16;
#pragma unroll
            for (int r = 0; r < 4; ++r) {
                int qrow = wave * 16 + lk * 4 + r;
                float w = __expf(s[j][r] * 0.125f - M[r]) * Li[r];
                int byte = (qrow * 256 + col * 4) ^ ((qrow & 7) << 4);
                *(float*)((char*)Ps + byte) = w;
            }
        }
        // Ps is read only by this wave below -> lgkmcnt fence, no barrier
        asm volatile("s_waitcnt lgkmcnt(0)" ::: "memory");

        // attn_weights: wave-local coalesced nontemporal float4 stores
        {
            size_t wbase = ((size_t)bh * 2048 + qt * 64 + wave * 16) * 2048
                         + (size_t)kt * 64;
#pragma unroll
            for (int l = 0; l < 4; ++l) {
                int idx = lane + l * 64;
                int q = idx >> 4, kq = idx & 15;
                int qrow = wave * 16 + q;
                int byte = (qrow * 256 + kq * 16) ^ ((qrow & 7) << 4);
                f32x4 v = *(const f32x4*)((const char*)Ps + byte);
                __builtin_nontemporal_store(v, (f32x4*)(wout + wbase + (size_t)q * 2048 + kq * 4));
            }
        }

        // PV: A = P (wave's 16 rows), B = V^T; bf16x3
        __builtin_amdgcn_s_setprio(1);
#pragma unroll
        for (int c = 0; c < 2; ++c) {
            int qrow = wave * 16 + l16;
            int b0 = qrow * 256 + c * 128 + lk * 32;
            int swz = (qrow & 7) << 4;
            float p[8];
            *(float4*)(p)     = *(const float4*)((const char*)Ps + (b0 ^ swz));
            *(float4*)(p + 4) = *(const float4*)((const char*)Ps + ((b0 + 16) ^ swz));
            bf16x8 pah, pal;
            split8(p, &pah, &pal);
#pragma unroll
            for (int j = 0; j < 4; ++j) {
                int d = j * 16 + l16;
                int byte = (d * 128 + c * 64 + lk * 16) ^ ((d & 7) << 4);
                bf16x8 vh = *(const bf16x8*)((const char*)Vh + byte);
                bf16x8 vl = *(const bf16x8*)((const char*)Vl + byte);
                accO[j] = __builtin_amdgcn_mfma_f32_16x16x32_bf16(pah, vh, accO[j], 0, 0, 0);
                accO[j] = __builtin_amdgcn_mfma_f32_16x16x32_bf16(pah, vl, accO[j], 0, 0, 0);
                accO[j] = __builtin_amdgcn_mfma_f32_16x16x32_bf16(pal, vh, accO[j], 0, 0, 0);
            }
        }
        __builtin_amdgcn_s_setprio(0);
    }

    // epilogue: AO [bh][t][64]; out row = lk*4+r, d = j*16+l16
#pragma unroll
    for (int j = 0; j < 4; ++j) {
        int d = j * 16 + l16;
#pragma unroll
        for (int r = 0; r < 4; ++r) {
            int row = qt * 64 + wave * 16 + lk * 4 + r;
            aout[((size_t)bh * 2048 + row) * 64 + d] = accO[j][r];
        }
    }
}

// ---------------------------------------------------------------------------
extern "C" void kernel_launch(void* const* d_in, const int* in_sizes, int n_in,
                              void* d_out, int out_size, void* d_ws, size_t ws_size,
                              hipStream_t stream) {
    const float* x  = (const float*)d_in[0];
    const float* Wq = (const float*)d_in[1];
    const float* Wk = (const float*)d_in[2];
    const float* Wv = (const float*)d_in[3];
    const float* Wo = (const float*)d_in[4];

    float* out0 = (float*)d_out;                       // [2,2048,1024]
    float* out1 = out0 + (size_t)MTOT * DM;            // attn_weights [2,16,2048,2048]

    float* ws   = (float*)d_ws;
    float* Qm   = ws;                                  // [B,H,T,64]
    float* Km   = Qm + (size_t)4194304;                // [B,H,T,64]
    float* VT   = Km + (size_t)4194304;                // [B,H,64,T]  (head-transposed V)
    float* AO   = VT + (size_t)4194304;                // attn_out [B,H,T,64]
    float* rmax = AO + (size_t)4194304;                // [32*2048]
    float* rsum = rmax + (size_t)65536;

    dim3 blk(256);
    dim3 gg(32, 8);
    gemm_bt_x3<<<gg, blk, 0, stream>>>(x, Wq, Qm, 0);
    gemm_bt_x3<<<gg, blk, 0, stream>>>(x, Wk, Km, 0);
    gemm_bt_x3<<<gg, blk, 0, stream>>>(x, Wv, VT, 2);

    dim3 ga(32, 32);
    rowstats<<<ga, blk, 0, stream>>>(Qm, Km, rmax, rsum);
    attn_pv<<<ga, blk, 0, stream>>>(Qm, Km, VT, rmax, rsum, out1, AO);

    gemm_bt_x3<<<gg, blk, 0, stream>>>(AO, Wo, out0, 1);
}